// Round 10
// baseline (1357.879 us; speedup 1.0000x reference)
//
#include <hip/hip_runtime.h>
#include <hip/hip_bf16.h>
#include <hip/hip_fp16.h>

// Inputs/outputs are FP32 (verified R3/R6).

constexpr int kB  = 128;
constexpr int kS  = 512;
constexpr int kT  = 64;
constexpr int kD  = 48;
constexpr int kFF = 128;
constexpr int kNH = 4;
constexpr int kHD = 12;

__device__ __forceinline__ void wsync(){
  __builtin_amdgcn_wave_barrier();
  asm volatile("" ::: "memory");
}

__device__ __forceinline__ float wsum(float v){
  #pragma unroll
  for(int o=32;o>=1;o>>=1) v += __shfl_xor(v,o,64);
  return v;
}

// pe[p, 2i] = sin(p * exp(-2i*ln(10000)/48)), pe[p, 2i+1] = cos(...)
__device__ __forceinline__ float pe_val(int p, int j){
  int i = j >> 1;
  float f = expf(-0.19188209108283716f * (float)(2*i));
  float a = (float)p * f;
  return (j & 1) ? cosf(a) : sinf(a);
}

union F4H8 { float4 f4; __half2 h2[4]; };

// dot of 48-float LDS vector with 48 fp16 weights held in LDS (encoder kernels)
__device__ __forceinline__ float dot48h(const float4* x, const __half* w){
  const float4* w4=(const float4*)w;
  float a=0.f;
  #pragma unroll
  for(int c=0;c<6;c++){
    F4H8 u; u.f4=w4[c];
    float2 f0=__half22float2(u.h2[0]), f1=__half22float2(u.h2[1]);
    float2 f2=__half22float2(u.h2[2]), f3=__half22float2(u.h2[3]);
    float4 x0=x[2*c], x1=x[2*c+1];
    a += x0.x*f0.x + x0.y*f0.y + x0.z*f1.x + x0.w*f1.y
       + x1.x*f2.x + x1.y*f2.y + x1.z*f3.x + x1.w*f3.y;
  }
  return a;
}
__device__ __forceinline__ float dot128h(const float4* x, const __half* w){
  const float4* w4=(const float4*)w;
  float a=0.f;
  #pragma unroll
  for(int c=0;c<16;c++){
    F4H8 u; u.f4=w4[c];
    float2 f0=__half22float2(u.h2[0]), f1=__half22float2(u.h2[1]);
    float2 f2=__half22float2(u.h2[2]), f3=__half22float2(u.h2[3]);
    float4 x0=x[2*c], x1=x[2*c+1];
    a += x0.x*f0.x + x0.y*f0.y + x0.z*f1.x + x0.w*f1.y
       + x1.x*f2.x + x1.y*f2.y + x1.z*f3.x + x1.w*f3.y;
  }
  return a;
}

// dot of 48-float LDS vector (broadcast-stream) with fp16 weight column in REGISTERS
__device__ __forceinline__ float dot48r(const float* vL, const float4* w6){
  const float4* v4=(const float4*)vL;
  float a=0.f;
  #pragma unroll
  for(int c=0;c<6;c++){
    F4H8 u; u.f4=w6[c];
    float2 f0=__half22float2(u.h2[0]), f1=__half22float2(u.h2[1]);
    float2 f2=__half22float2(u.h2[2]), f3=__half22float2(u.h2[3]);
    float4 x0=v4[2*c], x1=v4[2*c+1];
    a += x0.x*f0.x + x0.y*f0.y + x0.z*f1.x + x0.w*f1.y
       + x1.x*f2.x + x1.y*f2.y + x1.z*f3.x + x1.w*f3.y;
  }
  return a;
}
__device__ __forceinline__ float dot128r(const float* vL, const float4* w16){
  const float4* v4=(const float4*)vL;
  float a=0.f;
  #pragma unroll
  for(int c=0;c<16;c++){
    F4H8 u; u.f4=w16[c];
    float2 f0=__half22float2(u.h2[0]), f1=__half22float2(u.h2[1]);
    float2 f2=__half22float2(u.h2[2]), f3=__half22float2(u.h2[3]);
    float4 x0=v4[2*c], x1=v4[2*c+1];
    a += x0.x*f0.x + x0.y*f0.y + x0.z*f1.x + x0.w*f1.y
       + x1.x*f2.x + x1.y*f2.y + x1.z*f3.x + x1.w*f3.y;
  }
  return a;
}

// ---------------- K1: embed + PE -> X0 (fp32) ----------------
__global__ void k_embed(const float* __restrict__ src, const float* __restrict__ in_w,
                        const float* __restrict__ in_b, float* __restrict__ X0){
  int idx = blockIdx.x*256 + threadIdx.x;
  if (idx >= kB*kS*kD) return;
  int j = idx % kD; int bs = idx / kD; int s = bs % kS;
  float v = (src[bs] * in_w[j] + in_b[j]) * 6.928203230275509f;
  X0[idx] = v + pe_val(s, j);
}

// ---------------- K2: encoder QKV projection, fp16 W^T in LDS ----------------
__global__ void __launch_bounds__(256) k_qkv(const float* __restrict__ X,
    const float* __restrict__ wq, const float* __restrict__ bq,
    const float* __restrict__ wk, const float* __restrict__ bk,
    const float* __restrict__ wv, const float* __restrict__ bv,
    __half* __restrict__ Q, __half* __restrict__ K, __half* __restrict__ V){
  __shared__ __align__(16) __half W[3*2688];     // col stride 56 halves
  __shared__ __align__(16) float bias[3*kD];
  __shared__ __align__(16) float xt[32*kD];
  int tid = threadIdx.x;
  for (int i=tid;i<3*2304;i+=256){ int m=i/2304, e=i%2304, k=e/48, j=e%48;
    const float* w = (m==0)?wq:((m==1)?wk:wv);
    W[m*2688 + j*56 + k] = __float2half(w[e]); }
  for (int i=tid;i<3*kD;i+=256){ int m=i/kD,e=i%kD;
    const float* w=(m==0)?bq:((m==1)?bk:bv); bias[i]=w[e]; }
  long row0 = (long)blockIdx.x*32;
  for (int i=tid;i<32*kD;i+=256) xt[i] = X[row0*kD + i];
  __syncthreads();
  int r = tid>>3, c0 = tid&7;
  float4 xr[12];
  const float4* xp=(const float4*)(xt + r*kD);
  #pragma unroll
  for(int u=0;u<12;u++) xr[u]=xp[u];
  for (int c=c0; c<3*kD; c+=8){
    int m=c/kD, j=c%kD;
    float acc = bias[m*kD+j] + dot48h(xr, W + m*2688 + j*56);
    __half* o = (m==0)?Q:((m==1)?K:V);
    o[(row0+r)*kD+j]=__float2half(acc);
  }
}

// ---------------- K3: encoder attention — fp32 K/V staged in LDS ----------------
__global__ void __launch_bounds__(256) k_attn(const __half* Q, const __half* __restrict__ K,
                       const __half* __restrict__ V, __half* O){
  int b = blockIdx.x / kNH, h = blockIdx.x % kNH;
  __shared__ __align__(16) float Ks[kS*kHD];   // 24 KB, fp32 (no per-iter cvt)
  __shared__ __align__(16) float Vs[kS*kHD];
  int tid = threadIdx.x;
  long base = ((long)b*kS)*kD + h*kHD;
  for (int i=tid;i<kS*kHD;i+=256){ int r=i/kHD, d=i%kHD;
    Ks[i]=__half2float(K[base+(long)r*kD+d]);
    Vs[i]=__half2float(V[base+(long)r*kD+d]); }
  const float rs = 0.28867513459481287f;
  int q0 = tid, q1 = tid+256;
  float qa[kHD], qb[kHD];
  #pragma unroll
  for(int j=0;j<kHD;j++){
    qa[j]=__half2float(Q[base+(long)q0*kD+j])*rs;
    qb[j]=__half2float(Q[base+(long)q1*kD+j])*rs;
  }
  __syncthreads();
  float acc0[kHD], acc1[kHD];
  #pragma unroll
  for(int j=0;j<kHD;j++){ acc0[j]=0.f; acc1[j]=0.f; }
  float l0=0.f, l1=0.f;
  for(int k=0;k<kS;k++){
    const float4* kp=(const float4*)(Ks+k*kHD);  // broadcast reads
    const float4* vp=(const float4*)(Vs+k*kHD);
    float4 ka=kp[0], kb4=kp[1], kc4=kp[2];
    float kr[kHD]={ka.x,ka.y,ka.z,ka.w,kb4.x,kb4.y,kb4.z,kb4.w,kc4.x,kc4.y,kc4.z,kc4.w};
    float s0=0.f,s1=0.f;
    #pragma unroll
    for(int j=0;j<kHD;j++){ s0+=qa[j]*kr[j]; s1+=qb[j]*kr[j]; }
    float p0=__expf(s0), p1=__expf(s1);   // |s|<~42 << 88: exp-safe
    l0+=p0; l1+=p1;
    float4 va=vp[0], vb4=vp[1], vc4=vp[2];
    float vr[kHD]={va.x,va.y,va.z,va.w,vb4.x,vb4.y,vb4.z,vb4.w,vc4.x,vc4.y,vc4.z,vc4.w};
    #pragma unroll
    for(int j=0;j<kHD;j++){ acc0[j]+=p0*vr[j]; acc1[j]+=p1*vr[j]; }
  }
  float i0=1.f/l0, i1=1.f/l1;
  #pragma unroll
  for(int j=0;j<kHD;j++){
    O[base+(long)q0*kD+j]=__float2half(acc0[j]*i0);
    O[base+(long)q1*kD+j]=__float2half(acc1[j]*i1);
  }
}

// ---------------- K4: o-proj + residual + LN, fp16 W^T ----------------
__global__ void __launch_bounds__(256) k_oproj_ln(const float* __restrict__ Xres, const __half* __restrict__ O,
      const float* __restrict__ wo, const float* __restrict__ bo,
      const float* __restrict__ g, const float* __restrict__ bb,
      __half* __restrict__ Xout){
  __shared__ __align__(16) __half W[kD*56];
  __shared__ float bsh[kD], gs[kD], bs2[kD];
  __shared__ __align__(16) float res[32*kD];
  __shared__ __align__(16) float ot[32*kD];
  __shared__ float mrow[32], rstd[32];
  int tid=threadIdx.x;
  for(int i=tid;i<kD*kD;i+=256){ int k=i/48, j=i%48; W[j*56+k]=__float2half(wo[i]); }
  if(tid<kD){ bsh[tid]=bo[tid]; gs[tid]=g[tid]; bs2[tid]=bb[tid]; }
  long row0=(long)blockIdx.x*32;
  for(int i=tid;i<32*kD;i+=256) ot[i]=__half2float(O[row0*kD+i]);
  __syncthreads();
  int r=tid>>3, c0=tid&7;
  float4 orow[12];
  const float4* op=(const float4*)(ot + r*kD);
  #pragma unroll
  for(int u=0;u<12;u++) orow[u]=op[u];
  for(int j=c0;j<kD;j+=8){
    float acc=bsh[j]+dot48h(orow, W+j*56);
    res[r*kD+j]=Xres[row0*kD + r*kD + j]+acc;
  }
  __syncthreads();
  if(tid<32){
    float s=0.f, s2=0.f;
    for(int j=0;j<kD;j++){ float v=res[tid*kD+j]; s+=v; s2+=v*v; }
    float m=s*(1.f/kD);
    mrow[tid]=m; rstd[tid]=rsqrtf(s2*(1.f/kD)-m*m+1e-5f);
  }
  __syncthreads();
  for(int i=tid;i<32*kD;i+=256){int r2=i/kD,j=i%kD;
    Xout[row0*kD+i]=__float2half((res[i]-mrow[r2])*rstd[r2]*gs[j]+bs2[j]); }
}

// ---------------- K5: FFN + residual + LN, fp16 W^T ----------------
__global__ void __launch_bounds__(256) k_ffn_ln(const __half* __restrict__ Xin,
   const float* __restrict__ w1, const float* __restrict__ b1,
   const float* __restrict__ w2, const float* __restrict__ b2,
   const float* __restrict__ g, const float* __restrict__ bb,
   float* __restrict__ Xout){
  __shared__ __align__(16) __half W1[kFF*56];
  __shared__ __align__(16) __half W2[kD*136];
  __shared__ float b1s[kFF], b2s[kD], gs[kD], bs2[kD];
  __shared__ __align__(16) float xt[16*kD];
  __shared__ __align__(16) float h1v[16*kFF];
  __shared__ __align__(16) float res[16*kD];
  __shared__ float mrow[16], rstd[16];
  int tid=threadIdx.x;
  for(int i=tid;i<kD*kFF;i+=256){ int k=i/128, c=i%128; W1[c*56+k]=__float2half(w1[i]); }
  for(int i=tid;i<kFF*kD;i+=256){ int u=i/48, j=i%48; W2[j*136+u]=__float2half(w2[i]); }
  if(tid<kFF) b1s[tid]=b1[tid];
  if(tid<kD){ b2s[tid]=b2[tid]; gs[tid]=g[tid]; bs2[tid]=bb[tid]; }
  long row0=(long)blockIdx.x*16;
  for(int i=tid;i<16*kD;i+=256) xt[i]=__half2float(Xin[row0*kD+i]);
  __syncthreads();
  int r=tid>>4, c0=tid&15;
  {
    float4 xr[12];
    const float4* xp=(const float4*)(xt + r*kD);
    #pragma unroll
    for(int u=0;u<12;u++) xr[u]=xp[u];
    for(int c=c0;c<kFF;c+=16){
      float acc=b1s[c]+dot48h(xr, W1+c*56);
      h1v[r*kFF+c]=fmaxf(acc,0.f);
    }
  }
  __syncthreads();
  {
    float4 hr[32];
    const float4* hp=(const float4*)(h1v + r*kFF);
    #pragma unroll
    for(int u=0;u<32;u++) hr[u]=hp[u];
    for(int j=c0;j<kD;j+=16){
      float acc=b2s[j]+dot128h(hr, W2+j*136);
      res[r*kD+j]=xt[r*kD+j]+acc;
    }
  }
  __syncthreads();
  if(tid<16){
    float s=0.f, s2=0.f;
    for(int j=0;j<kD;j++){ float v=res[tid*kD+j]; s+=v; s2+=v*v; }
    float m=s*(1.f/kD);
    mrow[tid]=m; rstd[tid]=rsqrtf(s2*(1.f/kD)-m*m+1e-5f);
  }
  __syncthreads();
  for(int i=tid;i<16*kD;i+=256){int r2=i/kD,j=i%kD;
    Xout[row0*kD+i]=(res[i]-mrow[r2])*rstd[r2]*gs[j]+bs2[j]; }
}

// ---------------- K6: cross K/V projection, transposed fp16 out, fp16 W^T ----------------
__global__ void __launch_bounds__(256) k_ckv(const float* __restrict__ M,
    const float* __restrict__ wk, const float* __restrict__ bk,
    const float* __restrict__ wv, const float* __restrict__ bv,
    __half* __restrict__ Kc, __half* __restrict__ Vc){
  __shared__ __align__(16) __half W[2*2688];
  __shared__ float bias[2*kD];
  __shared__ __align__(16) float xt[32*kD];
  int tid=threadIdx.x;
  for(int i=tid;i<2*2304;i+=256){ int m=i/2304, e=i%2304, k=e/48, j=e%48;
    W[m*2688 + j*56 + k] = __float2half((m?wv:wk)[e]); }
  for(int i=tid;i<2*kD;i+=256){ int m=i/kD,e=i%kD; bias[i]=(m?bv:bk)[e]; }
  long row0=(long)blockIdx.x*32;
  for(int i=tid;i<32*kD;i+=256) xt[i]=M[row0*kD+i];
  __syncthreads();
  int r=tid>>3, c0=tid&7;
  float4 xr[12];
  const float4* xp=(const float4*)(xt + r*kD);
  #pragma unroll
  for(int u=0;u<12;u++) xr[u]=xp[u];
  long gr=row0+r; long bb2=gr>>9; long s=gr&511;
  for(int c=c0;c<2*kD;c+=8){
    int m=c/kD, j=c%kD;
    float acc=bias[m*kD+j]+dot48h(xr, W+m*2688+j*56);
    (m?Vc:Kc)[(bb2*kD+j)*kS+s]=__float2half(acc);
  }
}

// ---------------- K0: decoder weights -> padded FP16, column-major ----------------
// Wh halves: 6 mats 48 cols stride 56: swq@0 swk@2688 swv@5376 swo@8064 cwq@10752
// cwo@13440; w1 128 cols stride 56 @16128; w2 48 cols stride 136 @23296. Tot 29824.
__global__ void k_prep(const float* __restrict__ swq,const float* __restrict__ swk,
                       const float* __restrict__ swv,const float* __restrict__ swo,
                       const float* __restrict__ cwq,const float* __restrict__ cwo,
                       const float* __restrict__ w1,const float* __restrict__ w2,
                       __half* __restrict__ Wh){
  int idx=blockIdx.x*256+threadIdx.x;
  if(idx>=26112) return;
  if(idx<13824){
    int m=idx/2304, e=idx%2304, j=e/48, k=e%48;
    const float* w = (m==0)?swq:((m==1)?swk:((m==2)?swv:((m==3)?swo:((m==4)?cwq:cwo))));
    Wh[m*2688 + j*56 + k] = __float2half(w[k*48+j]);
  } else if(idx<19968){
    int e=idx-13824, c=e/48, k=e%48;
    Wh[16128 + c*56 + k] = __float2half(w1[k*128+c]);
  } else {
    int e=idx-19968, j=e/128, u=e%128;
    Wh[23296 + j*136 + u] = __float2half(w2[u*48+j]);
  }
}

// ---------------- K7: decoder v10 — weights in registers, stream-LDS reductions ----------------
// 4 barriers/step. All-wave redundant serial stages (identical inputs -> bitwise-
// identical outputs -> benign same-value LDS races; zero extra LDS traffic since
// weights live in registers). wsync (wave-ordered DS) validated by R7's pass.
struct DecP {
  const float *dec_start, *sbq, *sbk, *sbv, *sbo, *ln1g, *ln1b,
              *cbq, *cbo, *ln2g, *ln2b, *fb1, *fb2, *ln3g, *ln3b, *ow, *ob;
};

__global__ void __launch_bounds__(256,1) k_dec(const __half* __restrict__ KT,
    const __half* __restrict__ VT, const __half* __restrict__ Wg, DecP P,
    float* __restrict__ out){
  __shared__ __align__(16) float peL[kT*kD];       // 12 KB
  __shared__ __align__(16) float Krow[kT*52];      // self-K, row-major, pad 52
  __shared__ __align__(16) float Vt[kD*68];        // self-V, transposed [d][t], pad 68
  __shared__ __align__(16) float pS[kNH*64];
  __shared__ __align__(16) float xL[kD], qL[kD], soL[kD], rr1L[kD], h1L[kD],
                                 cqL[kD], covL[kD], rr2L[kD], h2L[kD],
                                 f1L[kFF], rr3L[kD];
  int tid=threadIdx.x, b=blockIdx.x, wave=tid>>6, lane=tid&63;
  const float rs=0.28867513459481287f;
  int cl = (lane<48)? lane : 47;    // clamp for weight-col loads

  for(int i=tid;i<kT*kD;i+=256) peL[i]=pe_val(i/kD,i%kD);

  // ---- per-lane fp16 weight columns in registers ----
  float4 wqkv[6], wso[6], wcq[6], wco[6], w1c[6], w2c[16];
  {
    int qkvbase = (wave==2)?2688:((wave==3)?5376:0);
    const float4* p1=(const float4*)(Wg + qkvbase + cl*56);
    const float4* p2=(const float4*)(Wg + 8064  + cl*56);
    const float4* p3=(const float4*)(Wg + 10752 + cl*56);
    const float4* p4=(const float4*)(Wg + 13440 + cl*56);
    int w1col = (wave<2)? (wave*64+lane) : lane;
    const float4* p5=(const float4*)(Wg + 16128 + w1col*56);
    const float4* p6=(const float4*)(Wg + 23296 + cl*136);
    #pragma unroll
    for(int c=0;c<6;c++){ wqkv[c]=p1[c]; wso[c]=p2[c]; wcq[c]=p3[c]; wco[c]=p4[c]; w1c[c]=p5[c]; }
    #pragma unroll
    for(int c=0;c<16;c++) w2c[c]=p6[c];
  }

  // per-lane constants
  float cur_l=0, c_sbo=0,c_cbo=0,c_fb2=0,c_cbq=0;
  float g1=0,bb1=0,g2=0,bb2=0,g3=0,bb3=0,c_ow=0;
  if(lane<48){
    cur_l=P.dec_start[lane];
    c_sbo=P.sbo[lane]; c_cbo=P.cbo[lane]; c_fb2=P.fb2[lane]; c_cbq=P.cbq[lane];
    g1=P.ln1g[lane]; bb1=P.ln1b[lane];
    g2=P.ln2g[lane]; bb2=P.ln2b[lane];
    g3=P.ln3g[lane]; bb3=P.ln3b[lane];
    c_ow=P.ow[lane];
  }
  float c_qkvb=0;
  if(lane<48 && wave>=1)
    c_qkvb = ((wave==1)?P.sbq:((wave==2)?P.sbk:P.sbv))[lane];
  float c_fb1 = (wave<2)? P.fb1[wave*64+lane] : 0.f;
  float c_ob = P.ob[0];

  // cross-attn K/V resident in registers: head = wave, 4 key-pairs per lane
  __half2 Kr[4][kHD], Vr[4][kHD];
  {
    const __half2* KTb=(const __half2*)KT + (long)b*kD*(kS/2);
    const __half2* VTb=(const __half2*)VT + (long)b*kD*(kS/2);
    #pragma unroll
    for(int i=0;i<4;i++){
      int pp=lane+64*i;
      #pragma unroll
      for(int u=0;u<kHD;u++){
        Kr[i][u]=KTb[(wave*kHD+u)*(kS/2)+pp];
        Vr[i][u]=VTb[(wave*kHD+u)*(kS/2)+pp];
      }
    }
  }
  __syncthreads();

  float x_l=0, h1_l=0, h2_l=0;
  for(int t=0;t<kT;t++){
    // S0 (all waves): x = cur + pe[t]; redundant same-value writes
    x_l = cur_l + peL[t*kD+cl];
    if(lane<48) xL[lane]=x_l;
    wsync();
    // S1 (waves 1-3): q/k/v column dots from register weights
    if(wave>=1 && lane<48){
      float a = c_qkvb + dot48r(xL, wqkv);
      if(wave==1) qL[lane]=a*rs;
      else if(wave==2) Krow[t*52+lane]=a;
      else Vt[lane*68+t]=a;
    }
    __syncthreads();                                 // B1
    // S2 (wave=head): scores -> p in LDS -> 12 lanes stream p.Vt (no shuffles)
    {
      int h=wave;
      float p=0.f;
      if(lane<=t){
        const float4* kp=(const float4*)(Krow+lane*52+h*kHD);
        const float4* qp=(const float4*)(qL+h*kHD);
        float4 q0=qp[0],q1=qp[1],q2=qp[2], k0=kp[0],k1=kp[1],k2=kp[2];
        float s=q0.x*k0.x+q0.y*k0.y+q0.z*k0.z+q0.w*k0.w
               +q1.x*k1.x+q1.y*k1.y+q1.z*k1.z+q1.w*k1.w
               +q2.x*k2.x+q2.y*k2.y+q2.z*k2.z+q2.w*k2.w;
        p=__expf(s);
      }
      pS[h*64+lane]=p;     // zeros beyond t -> masked sum for free
      wsync();
      if(lane<kHD){
        const float4* pp=(const float4*)(pS+h*64);
        const float4* vp=(const float4*)(Vt+(h*kHD+lane)*68);
        float sp=0.f, acc=0.f;
        #pragma unroll
        for(int c=0;c<16;c++){ float4 pc=pp[c], vc=vp[c];
          sp += pc.x+pc.y+pc.z+pc.w;
          acc+= pc.x*vc.x+pc.y*vc.y+pc.z*vc.z+pc.w*vc.w; }
        soL[h*kHD+lane]=acc/sp;
      }
    }
    __syncthreads();                                 // B2
    // S3 (all waves redundant): self o-proj + residual + LN1 + cross-q
    {
      float rr = x_l + c_sbo + dot48r(soL, wso);
      if(lane<48) rr1L[lane]=rr;
      wsync();
      const float4* r4=(const float4*)rr1L;
      float s=0.f,s2=0.f;
      #pragma unroll
      for(int c=0;c<12;c++){ float4 v=r4[c];
        s+=v.x+v.y+v.z+v.w; s2+=v.x*v.x+v.y*v.y+v.z*v.z+v.w*v.w; }
      float mean=s*(1.f/48.f), rstd=rsqrtf(s2*(1.f/48.f)-mean*mean+1e-5f);
      h1_l=(rr-mean)*rstd*g1+bb1;
      if(lane<48) h1L[lane]=h1_l;
      wsync();
      float cq = c_cbq + dot48r(h1L, wcq);
      if(lane<48) cqL[lane]=cq*rs;
      wsync();
    }
    // S4 (wave=head): cross-attn from registers
    {
      const float4* q4=(const float4*)(cqL+kHD*wave);
      float4 a0=q4[0],a1=q4[1],a2=q4[2];
      float qh[kHD]={a0.x,a0.y,a0.z,a0.w,a1.x,a1.y,a1.z,a1.w,a2.x,a2.y,a2.z,a2.w};
      float p[8], l=0.f;
      #pragma unroll
      for(int i=0;i<4;i++){
        float ax=0.f, ay=0.f;
        #pragma unroll
        for(int u=0;u<kHD;u++){ float2 kv=__half22float2(Kr[i][u]);
          ax+=qh[u]*kv.x; ay+=qh[u]*kv.y; }
        p[2*i]=__expf(ax); p[2*i+1]=__expf(ay);
        l+=p[2*i]+p[2*i+1];
      }
      l=wsum(l);
      float inv=1.f/l;
      float acc[kHD];
      #pragma unroll
      for(int u=0;u<kHD;u++) acc[u]=0.f;
      #pragma unroll
      for(int i=0;i<4;i++){
        #pragma unroll
        for(int u=0;u<kHD;u++){ float2 vv=__half22float2(Vr[i][u]);
          acc[u]+=p[2*i]*vv.x+p[2*i+1]*vv.y; }
      }
      #pragma unroll
      for(int u=0;u<kHD;u++) acc[u]=wsum(acc[u]);
      if(lane==0){
        #pragma unroll
        for(int u=0;u<kHD;u++) covL[wave*kHD+u]=acc[u]*inv;
      }
    }
    __syncthreads();                                 // B4
    // S5 (all waves redundant): cross o-proj + residual + LN2
    {
      float rr = h1_l + c_cbo + dot48r(covL, wco);
      if(lane<48) rr2L[lane]=rr;
      wsync();
      const float4* r4=(const float4*)rr2L;
      float s=0.f,s2=0.f;
      #pragma unroll
      for(int c=0;c<12;c++){ float4 v=r4[c];
        s+=v.x+v.y+v.z+v.w; s2+=v.x*v.x+v.y*v.y+v.z*v.z+v.w*v.w; }
      float mean=s*(1.f/48.f), rstd=rsqrtf(s2*(1.f/48.f)-mean*mean+1e-5f);
      h2_l=(rr-mean)*rstd*g2+bb2;
      if(lane<48) h2L[lane]=h2_l;
      wsync();
    }
    // S6 (waves 0,1): FFN1 (h2L written by own wave in S5 -> wsync sufficed)
    if(wave<2){
      float a = c_fb1 + dot48r(h2L, w1c);
      f1L[wave*64+lane]=fmaxf(a,0.f);
    }
    __syncthreads();                                 // B6
    // S7 (all waves redundant): FFN2 + residual + LN3 -> cur; wave0 writes y
    {
      float rr = h2_l + c_fb2 + dot128r(f1L, w2c);
      if(lane<48) rr3L[lane]=rr;
      wsync();
      const float4* r4=(const float4*)rr3L;
      float s=0.f,s2=0.f;
      #pragma unroll
      for(int c=0;c<12;c++){ float4 v=r4[c];
        s+=v.x+v.y+v.z+v.w; s2+=v.x*v.x+v.y*v.y+v.z*v.z+v.w*v.w; }
      float mean=s*(1.f/48.f), rstd=rsqrtf(s2*(1.f/48.f)-mean*mean+1e-5f);
      cur_l=(rr-mean)*rstd*g3+bb3;
      if(wave==0){
        float y=wsum((lane<48)? cur_l*c_ow : 0.f);
        if(lane==0) out[b*kT+t]=y+c_ob;
      }
    }
  }
}

extern "C" void kernel_launch(void* const* d_in, const int* in_sizes, int n_in,
                              void* d_out, int out_size, void* d_ws, size_t ws_size,
                              hipStream_t stream){
  // ws: Wh fp16 (reserve 65536 B), A fp32 NB, H1/H2/H3 fp16 NB each (~31.5 MiB).
  float* ws = (float*)d_ws;
  __half* Wh = (__half*)ws;
  const size_t NB = (size_t)kB*kS*kD;     // 3,145,728
  float*  A  = ws + 16384;
  __half* H1 = (__half*)(A + NB);
  __half* H2 = H1 + NB;
  __half* H3 = H2 + NB;

  k_embed<<<(kB*kS*kD+255)/256,256,0,stream>>>((const float*)d_in[0],(const float*)d_in[1],(const float*)d_in[2],A);
  k_qkv  <<<(kB*kS)/32,256,0,stream>>>(A,(const float*)d_in[4],(const float*)d_in[5],(const float*)d_in[6],
                                       (const float*)d_in[7],(const float*)d_in[8],(const float*)d_in[9],H1,H2,H3);
  k_attn <<<kB*kNH,256,0,stream>>>(H1,H2,H3,H1);
  k_oproj_ln<<<(kB*kS)/32,256,0,stream>>>(A,H1,(const float*)d_in[10],(const float*)d_in[11],
                                          (const float*)d_in[12],(const float*)d_in[13],H2);
  k_ffn_ln  <<<(kB*kS)/16,256,0,stream>>>(H2,(const float*)d_in[14],(const float*)d_in[15],(const float*)d_in[16],
                                          (const float*)d_in[17],(const float*)d_in[18],(const float*)d_in[19],A);
  k_ckv     <<<(kB*kS)/32,256,0,stream>>>(A,(const float*)d_in[32],(const float*)d_in[33],
                                          (const float*)d_in[34],(const float*)d_in[35],H1,H3);
  k_prep    <<<(26112+255)/256,256,0,stream>>>((const float*)d_in[20],(const float*)d_in[22],(const float*)d_in[24],
                                               (const float*)d_in[26],(const float*)d_in[30],(const float*)d_in[36],
                                               (const float*)d_in[40],(const float*)d_in[42],Wh);
  DecP P;
  P.dec_start=(const float*)d_in[3];
  P.sbq=(const float*)d_in[21]; P.sbk=(const float*)d_in[23]; P.sbv=(const float*)d_in[25]; P.sbo=(const float*)d_in[27];
  P.ln1g=(const float*)d_in[28]; P.ln1b=(const float*)d_in[29];
  P.cbq=(const float*)d_in[31]; P.cbo=(const float*)d_in[37];
  P.ln2g=(const float*)d_in[38]; P.ln2b=(const float*)d_in[39];
  P.fb1=(const float*)d_in[41]; P.fb2=(const float*)d_in[43];
  P.ln3g=(const float*)d_in[44]; P.ln3b=(const float*)d_in[45];
  P.ow=(const float*)d_in[46]; P.ob=(const float*)d_in[47];
  k_dec<<<kB,256,0,stream>>>(H1,H3,Wh,P,(float*)d_out);
}

// Round 11
// 896.261 us; speedup vs baseline: 1.5150x; 1.5150x over previous
//
#include <hip/hip_runtime.h>
#include <hip/hip_bf16.h>
#include <hip/hip_fp16.h>

// Inputs/outputs are FP32 (verified R3/R6).
// R10 lesson: KV-in-regs OR weights-in-regs — never both (VGPR cap 256 -> spill).

constexpr int kB  = 128;
constexpr int kS  = 512;
constexpr int kT  = 64;
constexpr int kD  = 48;
constexpr int kFF = 128;
constexpr int kNH = 4;
constexpr int kHD = 12;

__device__ __forceinline__ void wsync(){
  __builtin_amdgcn_wave_barrier();
  asm volatile("" ::: "memory");
}

__device__ __forceinline__ float wsum(float v){
  #pragma unroll
  for(int o=32;o>=1;o>>=1) v += __shfl_xor(v,o,64);
  return v;
}

// pe[p, 2i] = sin(p * exp(-2i*ln(10000)/48)), pe[p, 2i+1] = cos(...)
__device__ __forceinline__ float pe_val(int p, int j){
  int i = j >> 1;
  float f = expf(-0.19188209108283716f * (float)(2*i));
  float a = (float)p * f;
  return (j & 1) ? cosf(a) : sinf(a);
}

union F4H8 { float4 f4; __half2 h2[4]; };

// dot of 48-float x (12 float4, registers) with 48 fp16 LDS weights (6 chunks)
__device__ __forceinline__ float dot48h(const float4* x, const __half* w){
  const float4* w4=(const float4*)w;
  float a=0.f;
  #pragma unroll
  for(int c=0;c<6;c++){
    F4H8 u; u.f4=w4[c];
    float2 f0=__half22float2(u.h2[0]), f1=__half22float2(u.h2[1]);
    float2 f2=__half22float2(u.h2[2]), f3=__half22float2(u.h2[3]);
    float4 x0=x[2*c], x1=x[2*c+1];
    a += x0.x*f0.x + x0.y*f0.y + x0.z*f1.x + x0.w*f1.y
       + x1.x*f2.x + x1.y*f2.y + x1.z*f3.x + x1.w*f3.y;
  }
  return a;
}
__device__ __forceinline__ float dot128h(const float4* x, const __half* w){
  const float4* w4=(const float4*)w;
  float a=0.f;
  #pragma unroll
  for(int c=0;c<16;c++){
    F4H8 u; u.f4=w4[c];
    float2 f0=__half22float2(u.h2[0]), f1=__half22float2(u.h2[1]);
    float2 f2=__half22float2(u.h2[2]), f3=__half22float2(u.h2[3]);
    float4 x0=x[2*c], x1=x[2*c+1];
    a += x0.x*f0.x + x0.y*f0.y + x0.z*f1.x + x0.w*f1.y
       + x1.x*f2.x + x1.y*f2.y + x1.z*f3.x + x1.w*f3.y;
  }
  return a;
}
__device__ __forceinline__ float dot12f(const float4* x, const float4* k){
  float a=0.f;
  #pragma unroll
  for(int u=0;u<3;u++){ float4 xx=x[u], kk=k[u];
    a+=xx.x*kk.x+xx.y*kk.y+xx.z*kk.z+xx.w*kk.w; }
  return a;
}

// ---------------- K1: embed + PE -> X0 (fp32) ----------------
__global__ void k_embed(const float* __restrict__ src, const float* __restrict__ in_w,
                        const float* __restrict__ in_b, float* __restrict__ X0){
  int idx = blockIdx.x*256 + threadIdx.x;
  if (idx >= kB*kS*kD) return;
  int j = idx % kD; int bs = idx / kD; int s = bs % kS;
  float v = (src[bs] * in_w[j] + in_b[j]) * 6.928203230275509f;
  X0[idx] = v + pe_val(s, j);
}

// ---------------- K2: encoder QKV projection, fp16 W^T in LDS (R10) ----------------
__global__ void __launch_bounds__(256) k_qkv(const float* __restrict__ X,
    const float* __restrict__ wq, const float* __restrict__ bq,
    const float* __restrict__ wk, const float* __restrict__ bk,
    const float* __restrict__ wv, const float* __restrict__ bv,
    __half* __restrict__ Q, __half* __restrict__ K, __half* __restrict__ V){
  __shared__ __align__(16) __half W[3*2688];     // col stride 56 halves
  __shared__ __align__(16) float bias[3*kD];
  __shared__ __align__(16) float xt[32*kD];
  int tid = threadIdx.x;
  for (int i=tid;i<3*2304;i+=256){ int m=i/2304, e=i%2304, k=e/48, j=e%48;
    const float* w = (m==0)?wq:((m==1)?wk:wv);
    W[m*2688 + j*56 + k] = __float2half(w[e]); }
  for (int i=tid;i<3*kD;i+=256){ int m=i/kD,e=i%kD;
    const float* w=(m==0)?bq:((m==1)?bk:bv); bias[i]=w[e]; }
  long row0 = (long)blockIdx.x*32;
  for (int i=tid;i<32*kD;i+=256) xt[i] = X[row0*kD + i];
  __syncthreads();
  int r = tid>>3, c0 = tid&7;
  float4 xr[12];
  const float4* xp=(const float4*)(xt + r*kD);
  #pragma unroll
  for(int u=0;u<12;u++) xr[u]=xp[u];
  for (int c=c0; c<3*kD; c+=8){
    int m=c/kD, j=c%kD;
    float acc = bias[m*kD+j] + dot48h(xr, W + m*2688 + j*56);
    __half* o = (m==0)?Q:((m==1)?K:V);
    o[(row0+r)*kD+j]=__float2half(acc);
  }
}

// ---------------- K3: encoder attention — fp32 K/V staged in LDS (R10) ----------------
__global__ void __launch_bounds__(256) k_attn(const __half* Q, const __half* __restrict__ K,
                       const __half* __restrict__ V, __half* O){
  int b = blockIdx.x / kNH, h = blockIdx.x % kNH;
  __shared__ __align__(16) float Ks[kS*kHD];   // 24 KB, fp32 (no per-iter cvt)
  __shared__ __align__(16) float Vs[kS*kHD];
  int tid = threadIdx.x;
  long base = ((long)b*kS)*kD + h*kHD;
  for (int i=tid;i<kS*kHD;i+=256){ int r=i/kHD, d=i%kHD;
    Ks[i]=__half2float(K[base+(long)r*kD+d]);
    Vs[i]=__half2float(V[base+(long)r*kD+d]); }
  const float rs = 0.28867513459481287f;
  int q0 = tid, q1 = tid+256;
  float qa[kHD], qb[kHD];
  #pragma unroll
  for(int j=0;j<kHD;j++){
    qa[j]=__half2float(Q[base+(long)q0*kD+j])*rs;
    qb[j]=__half2float(Q[base+(long)q1*kD+j])*rs;
  }
  __syncthreads();
  float acc0[kHD], acc1[kHD];
  #pragma unroll
  for(int j=0;j<kHD;j++){ acc0[j]=0.f; acc1[j]=0.f; }
  float l0=0.f, l1=0.f;
  for(int k=0;k<kS;k++){
    const float4* kp=(const float4*)(Ks+k*kHD);  // broadcast reads
    const float4* vp=(const float4*)(Vs+k*kHD);
    float4 ka=kp[0], kb4=kp[1], kc4=kp[2];
    float kr[kHD]={ka.x,ka.y,ka.z,ka.w,kb4.x,kb4.y,kb4.z,kb4.w,kc4.x,kc4.y,kc4.z,kc4.w};
    float s0=0.f,s1=0.f;
    #pragma unroll
    for(int j=0;j<kHD;j++){ s0+=qa[j]*kr[j]; s1+=qb[j]*kr[j]; }
    float p0=__expf(s0), p1=__expf(s1);   // |s|<~42 << 88: exp-safe
    l0+=p0; l1+=p1;
    float4 va=vp[0], vb4=vp[1], vc4=vp[2];
    float vr[kHD]={va.x,va.y,va.z,va.w,vb4.x,vb4.y,vb4.z,vb4.w,vc4.x,vc4.y,vc4.z,vc4.w};
    #pragma unroll
    for(int j=0;j<kHD;j++){ acc0[j]+=p0*vr[j]; acc1[j]+=p1*vr[j]; }
  }
  float i0=1.f/l0, i1=1.f/l1;
  #pragma unroll
  for(int j=0;j<kHD;j++){
    O[base+(long)q0*kD+j]=__float2half(acc0[j]*i0);
    O[base+(long)q1*kD+j]=__float2half(acc1[j]*i1);
  }
}

// ---------------- K4: o-proj + residual + LN, fp16 W^T (R10) ----------------
__global__ void __launch_bounds__(256) k_oproj_ln(const float* __restrict__ Xres, const __half* __restrict__ O,
      const float* __restrict__ wo, const float* __restrict__ bo,
      const float* __restrict__ g, const float* __restrict__ bb,
      __half* __restrict__ Xout){
  __shared__ __align__(16) __half W[kD*56];
  __shared__ float bsh[kD], gs[kD], bs2[kD];
  __shared__ __align__(16) float res[32*kD];
  __shared__ __align__(16) float ot[32*kD];
  __shared__ float mrow[32], rstd[32];
  int tid=threadIdx.x;
  for(int i=tid;i<kD*kD;i+=256){ int k=i/48, j=i%48; W[j*56+k]=__float2half(wo[i]); }
  if(tid<kD){ bsh[tid]=bo[tid]; gs[tid]=g[tid]; bs2[tid]=bb[tid]; }
  long row0=(long)blockIdx.x*32;
  for(int i=tid;i<32*kD;i+=256) ot[i]=__half2float(O[row0*kD+i]);
  __syncthreads();
  int r=tid>>3, c0=tid&7;
  float4 orow[12];
  const float4* op=(const float4*)(ot + r*kD);
  #pragma unroll
  for(int u=0;u<12;u++) orow[u]=op[u];
  for(int j=c0;j<kD;j+=8){
    float acc=bsh[j]+dot48h(orow, W+j*56);
    res[r*kD+j]=Xres[row0*kD + r*kD + j]+acc;
  }
  __syncthreads();
  if(tid<32){
    float s=0.f, s2=0.f;
    for(int j=0;j<kD;j++){ float v=res[tid*kD+j]; s+=v; s2+=v*v; }
    float m=s*(1.f/kD);
    mrow[tid]=m; rstd[tid]=rsqrtf(s2*(1.f/kD)-m*m+1e-5f);
  }
  __syncthreads();
  for(int i=tid;i<32*kD;i+=256){int r2=i/kD,j=i%kD;
    Xout[row0*kD+i]=__float2half((res[i]-mrow[r2])*rstd[r2]*gs[j]+bs2[j]); }
}

// ---------------- K5: FFN + residual + LN, fp16 W^T (R10) ----------------
__global__ void __launch_bounds__(256) k_ffn_ln(const __half* __restrict__ Xin,
   const float* __restrict__ w1, const float* __restrict__ b1,
   const float* __restrict__ w2, const float* __restrict__ b2,
   const float* __restrict__ g, const float* __restrict__ bb,
   float* __restrict__ Xout){
  __shared__ __align__(16) __half W1[kFF*56];
  __shared__ __align__(16) __half W2[kD*136];
  __shared__ float b1s[kFF], b2s[kD], gs[kD], bs2[kD];
  __shared__ __align__(16) float xt[16*kD];
  __shared__ __align__(16) float h1v[16*kFF];
  __shared__ __align__(16) float res[16*kD];
  __shared__ float mrow[16], rstd[16];
  int tid=threadIdx.x;
  for(int i=tid;i<kD*kFF;i+=256){ int k=i/128, c=i%128; W1[c*56+k]=__float2half(w1[i]); }
  for(int i=tid;i<kFF*kD;i+=256){ int u=i/48, j=i%48; W2[j*136+u]=__float2half(w2[i]); }
  if(tid<kFF) b1s[tid]=b1[tid];
  if(tid<kD){ b2s[tid]=b2[tid]; gs[tid]=g[tid]; bs2[tid]=bb[tid]; }
  long row0=(long)blockIdx.x*16;
  for(int i=tid;i<16*kD;i+=256) xt[i]=__half2float(Xin[row0*kD+i]);
  __syncthreads();
  int r=tid>>4, c0=tid&15;
  {
    float4 xr[12];
    const float4* xp=(const float4*)(xt + r*kD);
    #pragma unroll
    for(int u=0;u<12;u++) xr[u]=xp[u];
    for(int c=c0;c<kFF;c+=16){
      float acc=b1s[c]+dot48h(xr, W1+c*56);
      h1v[r*kFF+c]=fmaxf(acc,0.f);
    }
  }
  __syncthreads();
  {
    float4 hr[32];
    const float4* hp=(const float4*)(h1v + r*kFF);
    #pragma unroll
    for(int u=0;u<32;u++) hr[u]=hp[u];
    for(int j=c0;j<kD;j+=16){
      float acc=b2s[j]+dot128h(hr, W2+j*136);
      res[r*kD+j]=xt[r*kD+j]+acc;
    }
  }
  __syncthreads();
  if(tid<16){
    float s=0.f, s2=0.f;
    for(int j=0;j<kD;j++){ float v=res[tid*kD+j]; s+=v; s2+=v*v; }
    float m=s*(1.f/kD);
    mrow[tid]=m; rstd[tid]=rsqrtf(s2*(1.f/kD)-m*m+1e-5f);
  }
  __syncthreads();
  for(int i=tid;i<16*kD;i+=256){int r2=i/kD,j=i%kD;
    Xout[row0*kD+i]=(res[i]-mrow[r2])*rstd[r2]*gs[j]+bs2[j]; }
}

// ---------------- K6: cross K/V projection, transposed fp16 out, fp16 W^T (R10) ----------------
__global__ void __launch_bounds__(256) k_ckv(const float* __restrict__ M,
    const float* __restrict__ wk, const float* __restrict__ bk,
    const float* __restrict__ wv, const float* __restrict__ bv,
    __half* __restrict__ Kc, __half* __restrict__ Vc){
  __shared__ __align__(16) __half W[2*2688];
  __shared__ float bias[2*kD];
  __shared__ __align__(16) float xt[32*kD];
  int tid=threadIdx.x;
  for(int i=tid;i<2*2304;i+=256){ int m=i/2304, e=i%2304, k=e/48, j=e%48;
    W[m*2688 + j*56 + k] = __float2half((m?wv:wk)[e]); }
  for(int i=tid;i<2*kD;i+=256){ int m=i/kD,e=i%kD; bias[i]=(m?bv:bk)[e]; }
  long row0=(long)blockIdx.x*32;
  for(int i=tid;i<32*kD;i+=256) xt[i]=M[row0*kD+i];
  __syncthreads();
  int r=tid>>3, c0=tid&7;
  float4 xr[12];
  const float4* xp=(const float4*)(xt + r*kD);
  #pragma unroll
  for(int u=0;u<12;u++) xr[u]=xp[u];
  long gr=row0+r; long bb2=gr>>9; long s=gr&511;
  for(int c=c0;c<2*kD;c+=8){
    int m=c/kD, j=c%kD;
    float acc=bias[m*kD+j]+dot48h(xr, W+m*2688+j*56);
    (m?Vc:Kc)[(bb2*kD+j)*kS+s]=__float2half(acc);
  }
}

// ---------------- K0: decoder weights -> padded FP16, column-major ----------------
// Wh halves: 6 mats 48 cols stride 56: swq@0 swk@2688 swv@5376 swo@8064 cwq@10752
// cwo@13440; w1 128 cols stride 56 @16128; w2 48 cols stride 136 @23296. Tot 29824.
__global__ void k_prep(const float* __restrict__ swq,const float* __restrict__ swk,
                       const float* __restrict__ swv,const float* __restrict__ swo,
                       const float* __restrict__ cwq,const float* __restrict__ cwo,
                       const float* __restrict__ w1,const float* __restrict__ w2,
                       __half* __restrict__ Wh){
  int idx=blockIdx.x*256+threadIdx.x;
  if(idx>=26112) return;
  if(idx<13824){
    int m=idx/2304, e=idx%2304, j=e/48, k=e%48;
    const float* w = (m==0)?swq:((m==1)?swk:((m==2)?swv:((m==3)?swo:((m==4)?cwq:cwo))));
    Wh[m*2688 + j*56 + k] = __float2half(w[k*48+j]);
  } else if(idx<19968){
    int e=idx-13824, c=e/48, k=e%48;
    Wh[16128 + c*56 + k] = __float2half(w1[k*128+c]);
  } else {
    int e=idx-19968, j=e/128, u=e%128;
    Wh[23296 + j*136 + u] = __float2half(w2[u*48+j]);
  }
}

// ---------------- K7: decoder — R8 verbatim (best measured: 451 µs, VGPR 140) ----------------
struct DecP {
  const float *dec_start, *sbq, *sbk, *sbv, *sbo, *ln1g, *ln1b,
              *cbq, *cbo, *ln2g, *ln2b, *fb1, *fb2, *ln3g, *ln3b, *ow, *ob;
};

__global__ void __launch_bounds__(256,1) k_dec(const __half* __restrict__ KT,
    const __half* __restrict__ VT, const __half* __restrict__ Wg, DecP P,
    float* __restrict__ out){
  __shared__ __align__(16) __half Wl[29824];       // fp16 weights, 58.25 KB
  __shared__ __align__(16) float Kh[kNH*kT*kHD];   // per-head self-K cache, 12 KB
  __shared__ __align__(16) float Vh[kNH*kT*kHD];
  __shared__ __align__(16) float qS[kNH*16];
  __shared__ __align__(16) float xvS[kD], soS[kD], h1S[kD], h2S[kD], cqS[kD], covS[kD];
  __shared__ __align__(16) float f1S[kFF];
  int tid=threadIdx.x, b=blockIdx.x, wave=tid>>6, lane=tid&63;
  const float rs=0.28867513459481287f;

  for(int i=tid;i<29824/8;i+=256) ((float4*)Wl)[i]=((const float4*)Wg)[i];

  // per-lane constants
  float cur=0, c_bo=0,c_cbq=0,c_cbo=0,c_fb2=0;
  float g1=0,bb1=0,g2=0,bb2=0,g3=0,bb3=0,c_ow=0;
  float c_qkvb=0, c_fb1=0;
  if(wave==0 && lane<kD){
    cur=P.dec_start[lane];
    c_bo=P.sbo[lane]; c_cbq=P.cbq[lane]; c_cbo=P.cbo[lane]; c_fb2=P.fb2[lane];
    g1=P.ln1g[lane]; bb1=P.ln1b[lane];
    g2=P.ln2g[lane]; bb2=P.ln2b[lane];
    g3=P.ln3g[lane]; bb3=P.ln3b[lane];
    c_ow=P.ow[lane];
  }
  if(wave>=1 && lane<kD)
    c_qkvb = ((wave==1)?P.sbq:((wave==2)?P.sbk:P.sbv))[lane];
  if(wave<2) c_fb1=P.fb1[wave*64+lane];
  float c_ob=P.ob[0];

  // cross-attn K/V resident in registers: head = wave, 4 key-pairs per lane
  __half2 Kr[4][kHD], Vr[4][kHD];
  {
    const __half2* KTb=(const __half2*)KT + (long)b*kD*(kS/2);
    const __half2* VTb=(const __half2*)VT + (long)b*kD*(kS/2);
    #pragma unroll
    for(int i=0;i<4;i++){
      int pp=lane+64*i;
      #pragma unroll
      for(int u=0;u<kHD;u++){
        Kr[i][u]=KTb[(wave*kHD+u)*(kS/2)+pp];
        Vr[i][u]=VTb[(wave*kHD+u)*(kS/2)+pp];
      }
    }
  }
  __syncthreads();

  float h1=0, h2=0, xv=0;
  for(int t=0;t<kT;t++){
    // stage0: wave0 publishes x
    if(wave==0 && lane<kD){ xv=cur+pe_val(t,lane); xvS[lane]=xv; }
    __syncthreads();                                   // B0
    // stage1: waves 1..3 compute q/k/v (m = wave-1)
    if(wave>=1 && lane<kD){
      int m=wave-1;
      float a=c_qkvb+dot48h((const float4*)xvS, Wl + m*2688 + lane*56);
      int hh=lane/kHD, dd=lane%kHD;
      if(m==0) qS[hh*16+dd]=a;
      else if(m==1) Kh[(hh*kT+t)*kHD+dd]=a;
      else          Vh[(hh*kT+t)*kHD+dd]=a;
    }
    __syncthreads();                                   // B1
    // stage2: self-attn, head = wave, lane = key; probs in regs
    {
      float p=0.f, pv[kHD];
      #pragma unroll
      for(int u=0;u<kHD;u++) pv[u]=0.f;
      if(lane<=t){
        float s=dot12f((const float4*)(qS+wave*16),
                       (const float4*)(Kh+(wave*kT+lane)*kHD))*rs;
        p=__expf(s);
        const float4* vp=(const float4*)(Vh+(wave*kT+lane)*kHD);
        float4 v0=vp[0], v1=vp[1], v2=vp[2];
        float vr[kHD]={v0.x,v0.y,v0.z,v0.w,v1.x,v1.y,v1.z,v1.w,v2.x,v2.y,v2.z,v2.w};
        #pragma unroll
        for(int u=0;u<kHD;u++) pv[u]=p*vr[u];
      }
      float l=wsum(p);
      #pragma unroll
      for(int u=0;u<kHD;u++) pv[u]=wsum(pv[u]);
      if(lane==0){
        float inv=1.f/l;
        #pragma unroll
        for(int u=0;u<kHD;u++) soS[wave*kHD+u]=pv[u]*inv;
      }
    }
    __syncthreads();                                   // B2
    // stage3: wave0 — self o-proj + residual + LN1 + cross-q
    if(wave==0){
      float rr=0.f;
      if(lane<kD)
        rr=xv+c_bo+dot48h((const float4*)soS, Wl+8064+lane*56);
      float s1=wsum(rr), s2=wsum(rr*rr);
      float mean=s1*(1.f/48.f);
      float rstd=rsqrtf(s2*(1.f/48.f)-mean*mean+1e-5f);
      h1=0;
      if(lane<kD){ h1=(rr-mean)*rstd*g1+bb1; h1S[lane]=h1; }
      wsync();
      if(lane<kD)
        cqS[lane]=c_cbq+dot48h((const float4*)h1S, Wl+10752+lane*56);
    }
    __syncthreads();                                   // B3
    // stage4: cross-attn from registers, head = wave
    {
      const float4* q4=(const float4*)cqS;
      float4 qq0=q4[wave*3], qq1=q4[wave*3+1], qq2=q4[wave*3+2];
      float qh[kHD]={qq0.x,qq0.y,qq0.z,qq0.w,qq1.x,qq1.y,qq1.z,qq1.w,qq2.x,qq2.y,qq2.z,qq2.w};
      #pragma unroll
      for(int u=0;u<kHD;u++) qh[u]*=rs;
      float p[8], l=0.f;
      #pragma unroll
      for(int i=0;i<4;i++){
        float ax=0.f, ay=0.f;
        #pragma unroll
        for(int u=0;u<kHD;u++){ float2 kv=__half22float2(Kr[i][u]);
          ax+=qh[u]*kv.x; ay+=qh[u]*kv.y; }
        p[2*i]=__expf(ax); p[2*i+1]=__expf(ay);
        l+=p[2*i]+p[2*i+1];
      }
      l=wsum(l);
      float inv=1.f/l;
      float acc[kHD];
      #pragma unroll
      for(int u=0;u<kHD;u++) acc[u]=0.f;
      #pragma unroll
      for(int i=0;i<4;i++){
        #pragma unroll
        for(int u=0;u<kHD;u++){ float2 vv=__half22float2(Vr[i][u]);
          acc[u]+=p[2*i]*vv.x+p[2*i+1]*vv.y; }
      }
      #pragma unroll
      for(int u=0;u<kHD;u++) acc[u]=wsum(acc[u]);
      if(lane==0){
        #pragma unroll
        for(int u=0;u<kHD;u++) covS[wave*kHD+u]=acc[u]*inv;
      }
    }
    __syncthreads();                                   // B4
    // stage5: wave0 — cross o-proj + residual + LN2
    if(wave==0){
      float rr=0.f;
      if(lane<kD)
        rr=h1+c_cbo+dot48h((const float4*)covS, Wl+13440+lane*56);
      float s1=wsum(rr), s2=wsum(rr*rr);
      float mean=s1*(1.f/48.f);
      float rstd=rsqrtf(s2*(1.f/48.f)-mean*mean+1e-5f);
      h2=0;
      if(lane<kD){ h2=(rr-mean)*rstd*g2+bb2; h2S[lane]=h2; }
    }
    __syncthreads();                                   // B5
    // stage6: FFN1 on waves 0,1 (col = wave*64 + lane)
    if(wave<2){
      int col=wave*64+lane;
      float a=c_fb1+dot48h((const float4*)h2S, Wl+16128+col*56);
      f1S[col]=fmaxf(a,0.f);
    }
    __syncthreads();                                   // B6
    // stage7: wave0 — FFN2 + residual + LN3 + output
    if(wave==0){
      float rr=0.f;
      if(lane<kD)
        rr=h2+c_fb2+dot128h((const float4*)f1S, Wl+23296+lane*136);
      float s1=wsum(rr), s2=wsum(rr*rr);
      float mean=s1*(1.f/48.f);
      float rstd=rsqrtf(s2*(1.f/48.f)-mean*mean+1e-5f);
      float cv=0.f;
      if(lane<kD){ cv=(rr-mean)*rstd*g3+bb3; cur=cv; }
      float y=wsum(cv*c_ow);
      if(lane==0) out[b*kT+t]=y+c_ob;
    }
  }
}

extern "C" void kernel_launch(void* const* d_in, const int* in_sizes, int n_in,
                              void* d_out, int out_size, void* d_ws, size_t ws_size,
                              hipStream_t stream){
  // ws: Wh fp16 (reserve 65536 B), A fp32 NB, H1/H2/H3 fp16 NB each (~31.5 MiB).
  float* ws = (float*)d_ws;
  __half* Wh = (__half*)ws;
  const size_t NB = (size_t)kB*kS*kD;     // 3,145,728
  float*  A  = ws + 16384;
  __half* H1 = (__half*)(A + NB);
  __half* H2 = H1 + NB;
  __half* H3 = H2 + NB;

  k_embed<<<(kB*kS*kD+255)/256,256,0,stream>>>((const float*)d_in[0],(const float*)d_in[1],(const float*)d_in[2],A);
  k_qkv  <<<(kB*kS)/32,256,0,stream>>>(A,(const float*)d_in[4],(const float*)d_in[5],(const float*)d_in[6],
                                       (const float*)d_in[7],(const float*)d_in[8],(const float*)d_in[9],H1,H2,H3);
  k_attn <<<kB*kNH,256,0,stream>>>(H1,H2,H3,H1);
  k_oproj_ln<<<(kB*kS)/32,256,0,stream>>>(A,H1,(const float*)d_in[10],(const float*)d_in[11],
                                          (const float*)d_in[12],(const float*)d_in[13],H2);
  k_ffn_ln  <<<(kB*kS)/16,256,0,stream>>>(H2,(const float*)d_in[14],(const float*)d_in[15],(const float*)d_in[16],
                                          (const float*)d_in[17],(const float*)d_in[18],(const float*)d_in[19],A);
  k_ckv     <<<(kB*kS)/32,256,0,stream>>>(A,(const float*)d_in[32],(const float*)d_in[33],
                                          (const float*)d_in[34],(const float*)d_in[35],H1,H3);
  k_prep    <<<(26112+255)/256,256,0,stream>>>((const float*)d_in[20],(const float*)d_in[22],(const float*)d_in[24],
                                               (const float*)d_in[26],(const float*)d_in[30],(const float*)d_in[36],
                                               (const float*)d_in[40],(const float*)d_in[42],Wh);
  DecP P;
  P.dec_start=(const float*)d_in[3];
  P.sbq=(const float*)d_in[21]; P.sbk=(const float*)d_in[23]; P.sbv=(const float*)d_in[25]; P.sbo=(const float*)d_in[27];
  P.ln1g=(const float*)d_in[28]; P.ln1b=(const float*)d_in[29];
  P.cbq=(const float*)d_in[31]; P.cbo=(const float*)d_in[37];
  P.ln2g=(const float*)d_in[38]; P.ln2b=(const float*)d_in[39];
  P.fb1=(const float*)d_in[41]; P.fb2=(const float*)d_in[43];
  P.ln3g=(const float*)d_in[44]; P.ln3b=(const float*)d_in[45];
  P.ow=(const float*)d_in[46]; P.ob=(const float*)d_in[47];
  k_dec<<<kB,256,0,stream>>>(H1,H3,Wh,P,(float*)d_out);
}